// Round 4
// baseline (79.623 us; speedup 1.0000x reference)
//
#include <hip/hip_runtime.h>

// RBFNN L1-distance, round 4: split-K for TLP.
// k_sim: 512 blocks x 256 threads. Each block: 64x64 output tile over a K=128
//   window (split-K=4) -> 2048 waves = 2 waves/SIMD, 2 blocks/CU.
//   LDS: f16 tiles packed row-major (64 rows x 16 granules of 16B) with XOR
//   granule swizzle slot = g ^ (row&7) -> fragment reads 2-way banked (free).
//   r=c=4 outputs/thread (16 acc) -> 1 B/pair LDS traffic (~33% LDS BW).
//   f16 math: v_pk_sub_f16 + v_and(abs) + v_dot2_f32_f16, f32 accumulate.
//   Partial tiles written to ws (4 x 2 MB).
// k_red: sum 4 partials -> S (d_out), per-block max -> bmax[512].
// k_out: global max from bmax, out = beta * (max*1.001 - sim) in place.

typedef _Float16 h2 __attribute__((ext_vector_type(2)));
typedef float f4 __attribute__((ext_vector_type(4)));
typedef unsigned int u32x4 __attribute__((ext_vector_type(4)));

#define DIM_K 512
#define DIM_O 512
#define NSPLIT 4
#define KW (DIM_K / NSPLIT)       // 128 k per block
#define PSTRIDE (1024 * 512)      // one partial plane, floats
#define W_DIST 1.001f

__device__ __forceinline__ h2 as_h2(unsigned int u){ h2 r; __builtin_memcpy(&r,&u,4); return r; }
__device__ __forceinline__ unsigned int cvt2(float a, float b){
    auto h = __builtin_amdgcn_cvt_pkrtz(a, b);   // __fp16x2; move bits via memcpy
    unsigned int r; __builtin_memcpy(&r, &h, 4); return r;
}

__global__ __launch_bounds__(256) void k_sim(const float* __restrict__ X,
                                             const float* __restrict__ C,
                                             float* __restrict__ P)
{
    // packed f16 tiles: row stride 64 dwords (256 B = 16 granules x 16 B)
    __shared__ __align__(16) unsigned int xs[64 * 64]; // 16 KB
    __shared__ __align__(16) unsigned int cs[64 * 64]; // 16 KB
    const int tid = threadIdx.x;
    const int b = blockIdx.x;
    const int ks = b & 3;           // k-split slice
    const int ct = (b >> 2) & 7;    // 8 col tiles
    const int rt = b >> 5;          // 16 row tiles
    const int row0 = rt * 64, col0 = ct * 64, kb = ks * KW;

    // ---- stage both tiles once (single barrier, no K loop) ----
    // granule s = tid + 256p: row = s>>4, LDS slot gI = s&15, fetch global
    // granule gg = gI ^ (row&7) so that compute reads slot g^(r&7) -> data g.
#pragma unroll
    for (int p = 0; p < 4; ++p) {
        const int s = tid + 256 * p;
        const int row = s >> 4, gI = s & 15, gg = gI ^ (row & 7);
        const float* xg = X + (row0 + row) * DIM_K + kb + gg * 8;
        f4 a = *(const f4*)xg; f4 bb = *(const f4*)(xg + 4);
        u32x4 w; w[0]=cvt2(a.x,a.y); w[1]=cvt2(a.z,a.w); w[2]=cvt2(bb.x,bb.y); w[3]=cvt2(bb.z,bb.w);
        *(u32x4*)&xs[row * 64 + gI * 4] = w;
        const float* cg = C + (col0 + row) * DIM_K + kb + gg * 8;
        a = *(const f4*)cg; bb = *(const f4*)(cg + 4);
        u32x4 v; v[0]=cvt2(a.x,a.y); v[1]=cvt2(a.z,a.w); v[2]=cvt2(bb.x,bb.y); v[3]=cvt2(bb.z,bb.w);
        *(u32x4*)&cs[row * 64 + gI * 4] = v;
    }
    __syncthreads();

    const int rb = (tid >> 4) * 4;  // rows rb..rb+3
    const int tc = tid & 15;        // cols tc + 16j
    float acc[4][4] = {};
    const h2 one2 = {(_Float16)1.f, (_Float16)1.f};

#pragma unroll
    for (int g = 0; g < 16; ++g) {  // 16 granules x 8 k
        u32x4 xr[4], cr[4];
#pragma unroll
        for (int i = 0; i < 4; ++i) {
            const int r = rb + i;
            xr[i] = *(const u32x4*)&xs[r * 64 + (g ^ (r & 7)) * 4]; // 16-lane bcast
        }
#pragma unroll
        for (int j = 0; j < 4; ++j) {
            const int c = tc + 16 * j;
            cr[j] = *(const u32x4*)&cs[c * 64 + (g ^ (c & 7)) * 4]; // 2-way banked
        }
#pragma unroll
        for (int k2 = 0; k2 < 4; ++k2) {
#pragma unroll
            for (int i = 0; i < 4; ++i) {
                const h2 a = as_h2(xr[i][k2]);
#pragma unroll
                for (int j = 0; j < 4; ++j) {
                    h2 d = a - as_h2(cr[j][k2]);            // v_pk_sub_f16
                    unsigned int du; __builtin_memcpy(&du, &d, 4);
                    h2 ad = as_h2(du & 0x7fff7fffu);        // abs both halves
                    acc[i][j] = __builtin_amdgcn_fdot2(ad, one2, acc[i][j], false);
                }
            }
        }
    }

    // ---- write partial tile ----
    float* Pk = P + ks * PSTRIDE;
#pragma unroll
    for (int i = 0; i < 4; ++i) {
        const int row = row0 + rb + i;
#pragma unroll
        for (int j = 0; j < 4; ++j)
            Pk[row * DIM_O + col0 + tc + 16 * j] = acc[i][j];
    }
}

__global__ __launch_bounds__(256) void k_red(const float* __restrict__ P,
                                             float* __restrict__ S,
                                             float* __restrict__ bmax)
{
    const int tid = threadIdx.x;
    const int f = blockIdx.x * 256 + tid;  // f4 index, 131072 total
    const f4* P4 = (const f4*)P;
    const int q = PSTRIDE / 4;
    f4 s = P4[f] + P4[f + q] + P4[f + 2 * q] + P4[f + 3 * q];
    ((f4*)S)[f] = s;
    float m = fmaxf(fmaxf(s.x, s.y), fmaxf(s.z, s.w));
#pragma unroll
    for (int off = 32; off > 0; off >>= 1)
        m = fmaxf(m, __shfl_xor(m, off, 64));
    __shared__ float wm[4];
    if ((tid & 63) == 0) wm[tid >> 6] = m;
    __syncthreads();
    if (tid == 0)
        bmax[blockIdx.x] = fmaxf(fmaxf(wm[0], wm[1]), fmaxf(wm[2], wm[3]));
}

__global__ __launch_bounds__(256) void k_out(float* __restrict__ S,
                                             const float* __restrict__ beta,
                                             const float* __restrict__ bmax)
{
    const int tid = threadIdx.x;
    const int lane = tid & 63;
    float m = 0.f;
#pragma unroll
    for (int i = 0; i < 8; ++i)            // 512 block maxes
        m = fmaxf(m, bmax[lane + 64 * i]);
#pragma unroll
    for (int off = 32; off > 0; off >>= 1)
        m = fmaxf(m, __shfl_xor(m, off, 64));
    const float shift = m * W_DIST;

    const int f = blockIdx.x * 256 + tid;  // f4 index, 131072 total
    f4 s = ((const f4*)S)[f];
    f4 b = ((const f4*)beta)[f & 127];
    f4 r;
    r.x = b.x * (shift - s.x);
    r.y = b.y * (shift - s.y);
    r.z = b.z * (shift - s.z);
    r.w = b.w * (shift - s.w);
    ((f4*)S)[f] = r;
}

extern "C" void kernel_launch(void* const* d_in, const int* in_sizes, int n_in,
                              void* d_out, int out_size, void* d_ws, size_t ws_size,
                              hipStream_t stream) {
    const float* X = (const float*)d_in[0];
    const float* C = (const float*)d_in[1];
    const float* beta = (const float*)d_in[2];
    float* S = (float*)d_out;
    float* P = (float*)d_ws;                       // 4 x 2 MB partial planes
    float* bmax = (float*)d_ws + NSPLIT * PSTRIDE; // 512 floats after partials
    k_sim<<<512, 256, 0, stream>>>(X, C, P);
    k_red<<<512, 256, 0, stream>>>(P, S, bmax);
    k_out<<<512, 256, 0, stream>>>(S, beta, bmax);
}